// Round 14
// baseline (148.657 us; speedup 1.0000x reference)
//
#include <hip/hip_runtime.h>
#include <hip/hip_bf16.h>

#define N_NODES 50000
#define N_EDGES 500000
#define H_DIM 128
#define OUT_DIM 16
#define KDIM 640  // 4*128 (bases) + 128 (self-loop features)

typedef short short8 __attribute__((ext_vector_type(8)));
typedef float f32x4 __attribute__((ext_vector_type(4)));
typedef float f32x2 __attribute__((ext_vector_type(2)));

__device__ inline unsigned short f2b(float f) {
  unsigned u = __float_as_uint(f);
  u += 0x7fffu + ((u >> 16) & 1u);
  return (unsigned short)(u >> 16);
}
__device__ inline float b2f(unsigned short u) {
  return __uint_as_float(((unsigned)u) << 16);
}

// async global->LDS, 16B per lane; LDS dest is wave-uniform base + lane*16 (linear)
__device__ __forceinline__ void gload_lds16(const unsigned short* g, unsigned short* l) {
  __builtin_amdgcn_global_load_lds(
      (const __attribute__((address_space(1))) unsigned int*)g,
      (__attribute__((address_space(3))) unsigned int*)l, 16, 0, 0);
}

// ---------------- tiny init: zero cntA + counter (must precede prologue's count section)
__global__ void init_kernel(int* __restrict__ cntA, int* __restrict__ counter) {
  int i = blockIdx.x * blockDim.x + threadIdx.x;
  if (i < N_NODES) cntA[i] = 0;
  if (i == 0) *counter = 0;
}

// ---------------- fused prologue: count | convert_x | pack B1t + B2pt
// count runs in the first 512 blocks and hides under the 6250 convert blocks.
#define COUNT_BLOCKS 512
#define CONV_BLOCKS 6250
#define PREP_BLOCKS 360
__global__ void prologue_kernel(const int* __restrict__ dst, int* __restrict__ cntA,
                                const int* __restrict__ node_ids, const float* __restrict__ emb,
                                unsigned short* __restrict__ Abuf,
                                const float* __restrict__ basis1, const float* __restrict__ loop_w1,
                                const float* __restrict__ basis2, const float* __restrict__ loop_w2,
                                unsigned short* __restrict__ B1t, unsigned short* __restrict__ B2pt) {
  int b = blockIdx.x;
  if (b < COUNT_BLOCKS) {
    for (int e = b * 256 + threadIdx.x; e < N_EDGES; e += COUNT_BLOCKS * 256)
      atomicAdd(&cntA[dst[e]], 1);
  } else if (b < COUNT_BLOCKS + CONV_BLOCKS) {
    int tid = (b - COUNT_BLOCKS) * 256 + threadIdx.x;  // one per 4 elems
    if (tid >= N_NODES * (H_DIM / 4)) return;
    int n = tid >> 5;
    int q = tid & 31;
    int id = node_ids[n];
    const float4 v = *reinterpret_cast<const float4*>(emb + (size_t)id * H_DIM + q * 4);
    uint2 p;
    p.x = (unsigned)f2b(v.x) | ((unsigned)f2b(v.y) << 16);
    p.y = (unsigned)f2b(v.z) | ((unsigned)f2b(v.w) << 16);
    *reinterpret_cast<uint2*>(Abuf + (size_t)n * KDIM + 512 + q * 4) = p;
  } else {
    int tid = (b - COUNT_BLOCKS - CONV_BLOCKS) * 256 + threadIdx.x;
    if (tid < 128 * KDIM) {
      int c = tid / KDIM, k = tid % KDIM;
      float v = (k < 512) ? basis1[k * 128 + c] : loop_w1[(k - 512) * 128 + c];
      B1t[c * KDIM + k] = f2b(v);
    } else if (tid < 128 * KDIM + 80 * 128) {
      int t2 = tid - 128 * KDIM;
      int c = t2 / 128, k = t2 % 128;
      float v = (c < 64) ? basis2[(c >> 4) * 128 * 16 + k * 16 + (c & 15)]
                         : loop_w2[k * 16 + (c - 64)];
      B2pt[c * 128 + k] = f2b(v);
    }
  }
}

__global__ void alloc_kernel(const int* __restrict__ cnt, int* __restrict__ start,
                             int* __restrict__ cursor, int* __restrict__ counter) {
  int i = blockIdx.x * blockDim.x + threadIdx.x;
  int lane = threadIdx.x & 63;
  int c = (i < N_NODES) ? cnt[i] : 0;
  int incl = c;
#pragma unroll
  for (int off = 1; off < 64; off <<= 1) {
    int v = __shfl_up(incl, off, 64);
    if (lane >= off) incl += v;
  }
  int waveTotal = __shfl(incl, 63, 64);
  int base = 0;
  if (lane == 63) base = atomicAdd(counter, waveTotal);
  base = __shfl(base, 63, 64);
  if (i < N_NODES) {
    int v = base + incl - c;
    start[i] = v;
    cursor[i] = v;  // fill's bump-allocator cursor (single atomic per edge)
  }
}

// edge record packed: src in bits 0:15 (N_NODES < 65536), etype in bits 16:31
__global__ void fill_kernel(const int* __restrict__ src, const int* __restrict__ dst,
                            const int* __restrict__ et, int* __restrict__ cursor,
                            unsigned* __restrict__ csr_se) {
  for (int e = blockIdx.x * blockDim.x + threadIdx.x; e < N_EDGES; e += gridDim.x * blockDim.x) {
    int idx = atomicAdd(&cursor[dst[e]], 1);
    csr_se[idx] = (unsigned)src[e] | ((unsigned)et[e] << 16);
  }
}

// ---------------- layer-1 aggregation: y[d,b,i] = (1/deg) * sum_e comp[et,b]*x[src,i]
__global__ __launch_bounds__(256) void agg_kernel(const int* __restrict__ csr_start,
                                                  const int* __restrict__ csr_cnt,
                                                  const unsigned* __restrict__ csr_se,
                                                  const float* __restrict__ comp,
                                                  unsigned short* __restrict__ Abuf) {
  int node = blockIdx.x * 4 + (threadIdx.x >> 6);
  if (node >= N_NODES) return;
  int lane = threadIdx.x & 63;
  int lo = __builtin_amdgcn_readfirstlane(csr_start[node]);
  int deg = __builtin_amdgcn_readfirstlane(csr_cnt[node]);
  int hi = lo + deg;

  f32x2 a0 = {0.f, 0.f}, a1 = {0.f, 0.f}, a2 = {0.f, 0.f}, a3 = {0.f, 0.f};
  const unsigned short* featb = Abuf + 512;
  const int laneoff = lane * 2;  // elements

#define EDGE_BODY(J)                                                                   \
  {                                                                                    \
    unsigned v = __builtin_amdgcn_readlane(myse, (J));                                 \
    int s = (int)(v & 0xFFFFu);                                                        \
    int t = (int)(v >> 16);                                                            \
    unsigned u = *reinterpret_cast<const unsigned*>(featb + s * KDIM + laneoff);       \
    float4 c = *reinterpret_cast<const float4*>(comp + t * 4);                         \
    f32x2 x;                                                                           \
    x.x = __uint_as_float(u << 16);                                                    \
    x.y = __uint_as_float(u & 0xffff0000u);                                            \
    a0 = __builtin_elementwise_fma((f32x2){c.x, c.x}, x, a0);                          \
    a1 = __builtin_elementwise_fma((f32x2){c.y, c.y}, x, a1);                          \
    a2 = __builtin_elementwise_fma((f32x2){c.z, c.z}, x, a2);                          \
    a3 = __builtin_elementwise_fma((f32x2){c.w, c.w}, x, a3);                          \
  }

  for (int e0 = lo; e0 < hi; e0 += 64) {
    int nchunk = min(hi - e0, 64);
    unsigned myse = 0;
    if (e0 + lane < hi) myse = csr_se[e0 + lane];
    int j = 0;
    for (; j + 8 <= nchunk; j += 8) {
      EDGE_BODY(j)
      EDGE_BODY(j + 1)
      EDGE_BODY(j + 2)
      EDGE_BODY(j + 3)
      EDGE_BODY(j + 4)
      EDGE_BODY(j + 5)
      EDGE_BODY(j + 6)
      EDGE_BODY(j + 7)
    }
    if (j + 4 <= nchunk) {
      EDGE_BODY(j)
      EDGE_BODY(j + 1)
      EDGE_BODY(j + 2)
      EDGE_BODY(j + 3)
      j += 4;
    }
    for (; j < nchunk; ++j) { EDGE_BODY(j) }
  }
#undef EDGE_BODY

  float inv = 1.0f / (float)(deg > 0 ? deg : 1);
  unsigned short* out = Abuf + (size_t)node * KDIM;
  unsigned p0w = (unsigned)f2b(a0.x * inv) | ((unsigned)f2b(a0.y * inv) << 16);
  unsigned p1w = (unsigned)f2b(a1.x * inv) | ((unsigned)f2b(a1.y * inv) << 16);
  unsigned p2w = (unsigned)f2b(a2.x * inv) | ((unsigned)f2b(a2.y * inv) << 16);
  unsigned p3w = (unsigned)f2b(a3.x * inv) | ((unsigned)f2b(a3.y * inv) << 16);
  *reinterpret_cast<unsigned*>(out + 0 * 128 + laneoff) = p0w;
  *reinterpret_cast<unsigned*>(out + 1 * 128 + laneoff) = p1w;
  *reinterpret_cast<unsigned*>(out + 2 * 128 + laneoff) = p2w;
  *reinterpret_cast<unsigned*>(out + 3 * 128 + laneoff) = p3w;
}

// ---------------- layer-2 aggregation over projected features (P in Abuf cols 0:80)
// Edge-pair processing: lanes 0-31 take edge j, lanes 32-63 edge j+1; each lane
// loads one dword (2 adjacent P columns) -> no sub-dword loads, half the VMEM ops.
__global__ __launch_bounds__(256) void agg2_kernel(const int* __restrict__ csr_start,
                                                   const int* __restrict__ csr_cnt,
                                                   const unsigned* __restrict__ csr_se,
                                                   const float* __restrict__ comp,
                                                   const unsigned short* __restrict__ Abuf,
                                                   const float* __restrict__ bias2,
                                                   float* __restrict__ dout) {
  int node = blockIdx.x * 4 + (threadIdx.x >> 6);
  if (node >= N_NODES) return;
  int lane = threadIdx.x & 63;
  int eg = lane >> 5;   // which edge of the pair
  int ll = lane & 31;
  int b = ll >> 3;      // basis index (c0>>4 == ll>>3)
  int c0 = ll * 2;      // P column pair (c0, c0+1), < 64
  int lo = __builtin_amdgcn_readfirstlane(csr_start[node]);
  int deg = __builtin_amdgcn_readfirstlane(csr_cnt[node]);
  int hi = lo + deg;

  f32x2 acc = {0.f, 0.f};

#define PAIR_BODY(J)                                                               \
  {                                                                               \
    int idx = (J) + eg;                                                           \
    unsigned v = __shfl(myse, idx, 64);                                           \
    int s = (int)(v & 0xFFFFu);                                                   \
    int t = (int)(v >> 16);                                                       \
    unsigned u = *reinterpret_cast<const unsigned*>(Abuf + (size_t)s * KDIM + c0);\
    float cv = comp[t * 4 + b];                                                   \
    float cb = (idx < nchunk) ? cv : 0.0f;                                        \
    f32x2 x;                                                                      \
    x.x = __uint_as_float(u << 16);                                               \
    x.y = __uint_as_float(u & 0xffff0000u);                                       \
    acc = __builtin_elementwise_fma((f32x2){cb, cb}, x, acc);                     \
  }

  for (int e0 = lo; e0 < hi; e0 += 64) {
    int nchunk = min(hi - e0, 64);
    unsigned myse = 0;
    if (e0 + lane < hi) myse = csr_se[e0 + lane];
    int j = 0;
    for (; j + 8 <= nchunk; j += 8) {
      PAIR_BODY(j)
      PAIR_BODY(j + 2)
      PAIR_BODY(j + 4)
      PAIR_BODY(j + 6)
    }
    for (; j < nchunk; j += 2) { PAIR_BODY(j) }
  }
#undef PAIR_BODY

  // sum over basis groups (xor 8, 16) and the two edge halves (xor 32)
  acc.x += __shfl_xor(acc.x, 8, 64);
  acc.y += __shfl_xor(acc.y, 8, 64);
  acc.x += __shfl_xor(acc.x, 16, 64);
  acc.y += __shfl_xor(acc.y, 16, 64);
  acc.x += __shfl_xor(acc.x, 32, 64);
  acc.y += __shfl_xor(acc.y, 32, 64);

  if (lane < 8) {
    float inv = 1.0f / (float)(deg > 0 ? deg : 1);
    unsigned su = *reinterpret_cast<const unsigned*>(Abuf + (size_t)node * KDIM + 64 + c0);
    float sl0 = __uint_as_float(su << 16);
    float sl1 = __uint_as_float(su & 0xffff0000u);
    float2 bv = *reinterpret_cast<const float2*>(bias2 + c0);
    float2 o;
    o.x = acc.x * inv + sl0 + bv.x;
    o.y = acc.y * inv + sl1 + bv.y;
    *reinterpret_cast<float2*>(dout + (size_t)node * OUT_DIM + c0) = o;
  }
}

// ---------------- fused GEMM1 + projection, LDS-aliased to 26KB (5 blocks/CU):
// main loop: As [0,8KB) + Bs [8,24KB); after final barrier Hs [0,16KB) aliases
// As+lower-Bs, B2pt stage Bp [16,26KB). h never touches HBM.
__global__ __launch_bounds__(256) void gemm1p_kernel(const unsigned short* __restrict__ A,
                                                     const unsigned short* __restrict__ B1t,
                                                     const float* __restrict__ bias1,
                                                     const unsigned short* __restrict__ B2pt,
                                                     unsigned short* __restrict__ Abuf, int M) {
  __shared__ unsigned short lds[13312];  // 26 KB
  unsigned short* Asb = lds;             // [0, 4096) shorts: A tile 64x64
  unsigned short* Bsb = lds + 4096;      // [4096, 12288): B tile 128x64
  unsigned short* Hs = lds;              // [0, 8192): h tile 64x128 (after main loop)
  unsigned short* Bp = lds + 8192;       // [8192, 13312): B2pt stage 80x64

  int wave = threadIdx.x >> 6;
  int lane = threadIdx.x & 63;
  int row0 = blockIdx.x * 64;
  int kh = lane >> 4;
  int cl = lane & 15;
  int ar = wave * 16 + cl;
  f32x4 acc[8] = {};

  for (int k0 = 0; k0 < KDIM; k0 += 64) {
#pragma unroll
    for (int p = 0; p < 2; ++p) {
      int cid = threadIdx.x + p * 256;
      int r = cid >> 3, c8 = cid & 7;
      int gr = row0 + r;  // rows >= M read ws garbage; their acc rows are never stored
      gload_lds16(A + (size_t)gr * KDIM + k0 + ((c8 ^ (r & 7)) * 8), Asb + cid * 8);
    }
#pragma unroll
    for (int p = 0; p < 4; ++p) {
      int cid = threadIdx.x + p * 256;
      int r = cid >> 3, c8 = cid & 7;
      gload_lds16(B1t + (size_t)r * KDIM + k0 + ((c8 ^ (r & 7)) * 8), Bsb + cid * 8);
    }
    __syncthreads();
    short8 a0 = *reinterpret_cast<const short8*>(Asb + ar * 64 + ((kh ^ (ar & 7)) * 8));
    short8 a1 = *reinterpret_cast<const short8*>(Asb + ar * 64 + (((4 + kh) ^ (ar & 7)) * 8));
#pragma unroll
    for (int ct = 0; ct < 8; ++ct) {
      int bc = ct * 16 + cl;
      short8 b0 = *reinterpret_cast<const short8*>(Bsb + bc * 64 + ((kh ^ (bc & 7)) * 8));
      short8 b1 = *reinterpret_cast<const short8*>(Bsb + bc * 64 + (((4 + kh) ^ (bc & 7)) * 8));
      acc[ct] = __builtin_amdgcn_mfma_f32_16x16x32_bf16(a0, b0, acc[ct], 0, 0, 0);
      acc[ct] = __builtin_amdgcn_mfma_f32_16x16x32_bf16(a1, b1, acc[ct], 0, 0, 0);
    }
    __syncthreads();
  }

  // epilogue 1: h -> Hs only (16B-chunk XOR swizzle); no global store
  int rb = wave * 16 + (lane >> 4) * 4;  // local row base
#pragma unroll
  for (int ct = 0; ct < 8; ++ct) {
    int col = ct * 16 + cl;
    float bv = bias1[col];
#pragma unroll
    for (int r = 0; r < 4; ++r) {
      int lr = rb + r;
      float v = fmaxf(acc[ct][r] + bv, 0.0f);
      unsigned short hb = f2b(v);
      int c8 = col >> 3;  // 0..15
      int c8s = (c8 & 8) | ((c8 ^ lr) & 7);
      *reinterpret_cast<unsigned short*>(
          reinterpret_cast<char*>(Hs + lr * 128) + c8s * 16 + (col & 7) * 2) = hb;
    }
  }
  __syncthreads();

  // P-GEMM: A = Hs (64x128), B = B2pt [80][128] staged into Bp
  f32x4 acc2[5] = {};
  for (int k0 = 0; k0 < 128; k0 += 64) {
    for (int cid = threadIdx.x; cid < 80 * 8; cid += 256) {
      int r = cid >> 3, c8 = cid & 7;
      short8 v = *reinterpret_cast<const short8*>(B2pt + r * 128 + k0 + c8 * 8);
      *reinterpret_cast<short8*>(Bp + r * 64 + (c8 ^ (r & 7)) * 8) = v;
    }
    __syncthreads();
    int c8a = (k0 >> 3) + kh;
    int c8b = (k0 >> 3) + 4 + kh;
    short8 h0 = *reinterpret_cast<const short8*>(
        reinterpret_cast<char*>(Hs + ar * 128) + (((c8a ^ ar) & 7) | (c8a & 8)) * 16);
    short8 h1 = *reinterpret_cast<const short8*>(
        reinterpret_cast<char*>(Hs + ar * 128) + (((c8b ^ ar) & 7) | (c8b & 8)) * 16);
#pragma unroll
    for (int ct = 0; ct < 5; ++ct) {
      int bc = ct * 16 + cl;
      short8 b0 = *reinterpret_cast<const short8*>(Bp + bc * 64 + ((kh ^ (bc & 7)) * 8));
      short8 b1 = *reinterpret_cast<const short8*>(Bp + bc * 64 + (((4 + kh) ^ (bc & 7)) * 8));
      acc2[ct] = __builtin_amdgcn_mfma_f32_16x16x32_bf16(h0, b0, acc2[ct], 0, 0, 0);
      acc2[ct] = __builtin_amdgcn_mfma_f32_16x16x32_bf16(h1, b1, acc2[ct], 0, 0, 0);
    }
    __syncthreads();
  }

  // epilogue 2: P -> Abuf cols 0:80
#pragma unroll
  for (int ct = 0; ct < 5; ++ct) {
    int col = ct * 16 + cl;
#pragma unroll
    for (int r = 0; r < 4; ++r) {
      int gr = row0 + rb + r;
      if (gr < M) Abuf[(size_t)gr * KDIM + col] = f2b(acc2[ct][r]);
    }
  }
}

extern "C" void kernel_launch(void* const* d_in, const int* in_sizes, int n_in,
                              void* d_out, int out_size, void* d_ws, size_t ws_size,
                              hipStream_t stream) {
  const int* node_ids = (const int*)d_in[0];
  const int* src = (const int*)d_in[1];
  const int* dst = (const int*)d_in[2];
  const int* etype = (const int*)d_in[3];
  const float* emb = (const float*)d_in[4];
  const float* basis1 = (const float*)d_in[5];
  const float* comp1 = (const float*)d_in[6];
  const float* loop_w1 = (const float*)d_in[7];
  const float* bias1 = (const float*)d_in[8];
  const float* basis2 = (const float*)d_in[9];
  const float* comp2 = (const float*)d_in[10];
  const float* loop_w2 = (const float*)d_in[11];
  const float* bias2 = (const float*)d_in[12];
  (void)in_sizes; (void)n_in; (void)out_size; (void)ws_size;

  char* ws = (char*)d_ws;
  size_t off = 0;
  auto alloc = [&](size_t bytes) -> void* {
    void* p = ws + off;
    off += (bytes + 255) & ~(size_t)255;
    return p;
  };
  int* csr_start = (int*)alloc(N_NODES * sizeof(int));
  int* cntA = (int*)alloc(N_NODES * sizeof(int));
  int* cursor = (int*)alloc(N_NODES * sizeof(int));
  int* counter = (int*)alloc(sizeof(int));
  unsigned* csr_se = (unsigned*)alloc((size_t)N_EDGES * sizeof(unsigned));
  unsigned short* Abuf = (unsigned short*)alloc((size_t)N_NODES * KDIM * sizeof(unsigned short));
  unsigned short* B1t = (unsigned short*)alloc(128 * KDIM * sizeof(unsigned short));
  unsigned short* B2pt = (unsigned short*)alloc(80 * 128 * sizeof(unsigned short));

  init_kernel<<<(N_NODES + 255) / 256, 256, 0, stream>>>(cntA, counter);
  prologue_kernel<<<COUNT_BLOCKS + CONV_BLOCKS + PREP_BLOCKS, 256, 0, stream>>>(
      dst, cntA, node_ids, emb, Abuf, basis1, loop_w1, basis2, loop_w2, B1t, B2pt);
  alloc_kernel<<<(N_NODES + 255) / 256, 256, 0, stream>>>(cntA, csr_start, cursor, counter);
  fill_kernel<<<1024, 256, 0, stream>>>(src, dst, etype, cursor, csr_se);

  // layer 1: aggregate x -> y1s (cols 0:512), then fused GEMM:
  // h (LDS only) and P = h*[basis2|loop_w2] -> cols 0:80
  agg_kernel<<<(N_NODES + 3) / 4, 256, 0, stream>>>(csr_start, cntA, csr_se, comp1, Abuf);
  gemm1p_kernel<<<(N_NODES + 63) / 64, 256, 0, stream>>>(Abuf, B1t, bias1, B2pt, Abuf, N_NODES);

  // layer 2: agg over P + self-loop + bias2 -> d_out (fp32)
  agg2_kernel<<<(N_NODES + 3) / 4, 256, 0, stream>>>(csr_start, cntA, csr_se, comp2, Abuf,
                                                     bias2, (float*)d_out);
}

// Round 15
// 148.290 us; speedup vs baseline: 1.0025x; 1.0025x over previous
//
#include <hip/hip_runtime.h>
#include <hip/hip_bf16.h>

#define N_NODES 50000
#define N_EDGES 500000
#define H_DIM 128
#define OUT_DIM 16
#define KDIM 640  // 4*128 (bases) + 128 (self-loop features)

typedef short short8 __attribute__((ext_vector_type(8)));
typedef float f32x4 __attribute__((ext_vector_type(4)));
typedef float f32x2 __attribute__((ext_vector_type(2)));

__device__ inline unsigned short f2b(float f) {
  unsigned u = __float_as_uint(f);
  u += 0x7fffu + ((u >> 16) & 1u);
  return (unsigned short)(u >> 16);
}
__device__ inline float b2f(unsigned short u) {
  return __uint_as_float(((unsigned)u) << 16);
}

// async global->LDS, 16B per lane; LDS dest is wave-uniform base + lane*16 (linear)
__device__ __forceinline__ void gload_lds16(const unsigned short* g, unsigned short* l) {
  __builtin_amdgcn_global_load_lds(
      (const __attribute__((address_space(1))) unsigned int*)g,
      (__attribute__((address_space(3))) unsigned int*)l, 16, 0, 0);
}

// ---------------- fused prologue: convert_x | pack B1t [128][640] + B2pt [80][128] | init
#define CONV_BLOCKS 6250
#define PREP_BLOCKS 360
#define INIT_BLOCKS 196
__global__ void prologue_kernel(const int* __restrict__ node_ids, const float* __restrict__ emb,
                                unsigned short* __restrict__ Abuf,
                                const float* __restrict__ basis1, const float* __restrict__ loop_w1,
                                const float* __restrict__ basis2, const float* __restrict__ loop_w2,
                                unsigned short* __restrict__ B1t, unsigned short* __restrict__ B2pt,
                                int* __restrict__ cntA, int* __restrict__ counter) {
  int b = blockIdx.x;
  if (b < CONV_BLOCKS) {
    int tid = b * 256 + threadIdx.x;  // one per 4 elems
    if (tid >= N_NODES * (H_DIM / 4)) return;
    int n = tid >> 5;
    int q = tid & 31;
    int id = node_ids[n];
    const float4 v = *reinterpret_cast<const float4*>(emb + (size_t)id * H_DIM + q * 4);
    uint2 p;
    p.x = (unsigned)f2b(v.x) | ((unsigned)f2b(v.y) << 16);
    p.y = (unsigned)f2b(v.z) | ((unsigned)f2b(v.w) << 16);
    *reinterpret_cast<uint2*>(Abuf + (size_t)n * KDIM + 512 + q * 4) = p;
  } else if (b < CONV_BLOCKS + PREP_BLOCKS) {
    int tid = (b - CONV_BLOCKS) * 256 + threadIdx.x;
    if (tid < 128 * KDIM) {
      int c = tid / KDIM, k = tid % KDIM;
      float v = (k < 512) ? basis1[k * 128 + c] : loop_w1[(k - 512) * 128 + c];
      B1t[c * KDIM + k] = f2b(v);
    } else if (tid < 128 * KDIM + 80 * 128) {
      int t2 = tid - 128 * KDIM;
      int c = t2 / 128, k = t2 % 128;
      float v = (c < 64) ? basis2[(c >> 4) * 128 * 16 + k * 16 + (c & 15)]
                         : loop_w2[k * 16 + (c - 64)];
      B2pt[c * 128 + k] = f2b(v);
    }
  } else {
    int i = (b - CONV_BLOCKS - PREP_BLOCKS) * 256 + threadIdx.x;
    if (i < N_NODES) cntA[i] = 0;
    if (i == 0) *counter = 0;
  }
}

// ---------------- CSR build (segment allocator; order-free)
__global__ void count_kernel(const int* __restrict__ dst, int* __restrict__ cnt) {
  for (int e = blockIdx.x * blockDim.x + threadIdx.x; e < N_EDGES; e += gridDim.x * blockDim.x)
    atomicAdd(&cnt[dst[e]], 1);
}

__global__ void alloc_kernel(const int* __restrict__ cnt, int* __restrict__ start,
                             int* __restrict__ cursor, int* __restrict__ counter) {
  int i = blockIdx.x * blockDim.x + threadIdx.x;
  int lane = threadIdx.x & 63;
  int c = (i < N_NODES) ? cnt[i] : 0;
  int incl = c;
#pragma unroll
  for (int off = 1; off < 64; off <<= 1) {
    int v = __shfl_up(incl, off, 64);
    if (lane >= off) incl += v;
  }
  int waveTotal = __shfl(incl, 63, 64);
  int base = 0;
  if (lane == 63) base = atomicAdd(counter, waveTotal);
  base = __shfl(base, 63, 64);
  if (i < N_NODES) {
    int v = base + incl - c;
    start[i] = v;
    cursor[i] = v;  // fill's bump-allocator cursor (single atomic per edge)
  }
}

// edge record packed: src in bits 0:15 (N_NODES < 65536), etype in bits 16:31
__global__ void fill_kernel(const int* __restrict__ src, const int* __restrict__ dst,
                            const int* __restrict__ et, int* __restrict__ cursor,
                            unsigned* __restrict__ csr_se) {
  for (int e = blockIdx.x * blockDim.x + threadIdx.x; e < N_EDGES; e += gridDim.x * blockDim.x) {
    int idx = atomicAdd(&cursor[dst[e]], 1);
    csr_se[idx] = (unsigned)src[e] | ((unsigned)et[e] << 16);
  }
}

// ---------------- layer-1 aggregation: y[d,b,i] = (1/deg) * sum_e comp[et,b]*x[src,i]
__global__ __launch_bounds__(256) void agg_kernel(const int* __restrict__ csr_start,
                                                  const int* __restrict__ csr_cnt,
                                                  const unsigned* __restrict__ csr_se,
                                                  const float* __restrict__ comp,
                                                  unsigned short* __restrict__ Abuf) {
  int node = blockIdx.x * 4 + (threadIdx.x >> 6);
  if (node >= N_NODES) return;
  int lane = threadIdx.x & 63;
  int lo = __builtin_amdgcn_readfirstlane(csr_start[node]);
  int deg = __builtin_amdgcn_readfirstlane(csr_cnt[node]);
  int hi = lo + deg;

  f32x2 a0 = {0.f, 0.f}, a1 = {0.f, 0.f}, a2 = {0.f, 0.f}, a3 = {0.f, 0.f};
  const unsigned short* featb = Abuf + 512;
  const int laneoff = lane * 2;  // elements

#define EDGE_BODY(J)                                                                   \
  {                                                                                    \
    unsigned v = __builtin_amdgcn_readlane(myse, (J));                                 \
    int s = (int)(v & 0xFFFFu);                                                        \
    int t = (int)(v >> 16);                                                            \
    unsigned u = *reinterpret_cast<const unsigned*>(featb + s * KDIM + laneoff);       \
    float4 c = *reinterpret_cast<const float4*>(comp + t * 4);                         \
    f32x2 x;                                                                           \
    x.x = __uint_as_float(u << 16);                                                    \
    x.y = __uint_as_float(u & 0xffff0000u);                                            \
    a0 = __builtin_elementwise_fma((f32x2){c.x, c.x}, x, a0);                          \
    a1 = __builtin_elementwise_fma((f32x2){c.y, c.y}, x, a1);                          \
    a2 = __builtin_elementwise_fma((f32x2){c.z, c.z}, x, a2);                          \
    a3 = __builtin_elementwise_fma((f32x2){c.w, c.w}, x, a3);                          \
  }

  for (int e0 = lo; e0 < hi; e0 += 64) {
    int nchunk = min(hi - e0, 64);
    unsigned myse = 0;
    if (e0 + lane < hi) myse = csr_se[e0 + lane];
    int j = 0;
    for (; j + 8 <= nchunk; j += 8) {
      EDGE_BODY(j)
      EDGE_BODY(j + 1)
      EDGE_BODY(j + 2)
      EDGE_BODY(j + 3)
      EDGE_BODY(j + 4)
      EDGE_BODY(j + 5)
      EDGE_BODY(j + 6)
      EDGE_BODY(j + 7)
    }
    if (j + 4 <= nchunk) {
      EDGE_BODY(j)
      EDGE_BODY(j + 1)
      EDGE_BODY(j + 2)
      EDGE_BODY(j + 3)
      j += 4;
    }
    for (; j < nchunk; ++j) { EDGE_BODY(j) }
  }
#undef EDGE_BODY

  float inv = 1.0f / (float)(deg > 0 ? deg : 1);
  unsigned short* out = Abuf + (size_t)node * KDIM;
  unsigned p0w = (unsigned)f2b(a0.x * inv) | ((unsigned)f2b(a0.y * inv) << 16);
  unsigned p1w = (unsigned)f2b(a1.x * inv) | ((unsigned)f2b(a1.y * inv) << 16);
  unsigned p2w = (unsigned)f2b(a2.x * inv) | ((unsigned)f2b(a2.y * inv) << 16);
  unsigned p3w = (unsigned)f2b(a3.x * inv) | ((unsigned)f2b(a3.y * inv) << 16);
  *reinterpret_cast<unsigned*>(out + 0 * 128 + laneoff) = p0w;
  *reinterpret_cast<unsigned*>(out + 1 * 128 + laneoff) = p1w;
  *reinterpret_cast<unsigned*>(out + 2 * 128 + laneoff) = p2w;
  *reinterpret_cast<unsigned*>(out + 3 * 128 + laneoff) = p3w;
}

// ---------------- layer-2 aggregation over projected features (P in Abuf cols 0:80)
// Edge-pair processing: lanes 0-31 take edge j, lanes 32-63 edge j+1; each lane
// loads one dword (2 adjacent P columns) -> no sub-dword loads, half the VMEM ops.
__global__ __launch_bounds__(256) void agg2_kernel(const int* __restrict__ csr_start,
                                                   const int* __restrict__ csr_cnt,
                                                   const unsigned* __restrict__ csr_se,
                                                   const float* __restrict__ comp,
                                                   const unsigned short* __restrict__ Abuf,
                                                   const float* __restrict__ bias2,
                                                   float* __restrict__ dout) {
  int node = blockIdx.x * 4 + (threadIdx.x >> 6);
  if (node >= N_NODES) return;
  int lane = threadIdx.x & 63;
  int eg = lane >> 5;   // which edge of the pair
  int ll = lane & 31;
  int b = ll >> 3;      // basis index (c0>>4 == ll>>3)
  int c0 = ll * 2;      // P column pair (c0, c0+1), < 64
  int lo = __builtin_amdgcn_readfirstlane(csr_start[node]);
  int deg = __builtin_amdgcn_readfirstlane(csr_cnt[node]);
  int hi = lo + deg;

  f32x2 acc = {0.f, 0.f};

#define PAIR_BODY(J)                                                               \
  {                                                                               \
    int idx = (J) + eg;                                                           \
    unsigned v = __shfl(myse, idx, 64);                                           \
    int s = (int)(v & 0xFFFFu);                                                   \
    int t = (int)(v >> 16);                                                       \
    unsigned u = *reinterpret_cast<const unsigned*>(Abuf + (size_t)s * KDIM + c0);\
    float cv = comp[t * 4 + b];                                                   \
    float cb = (idx < nchunk) ? cv : 0.0f;                                        \
    f32x2 x;                                                                      \
    x.x = __uint_as_float(u << 16);                                               \
    x.y = __uint_as_float(u & 0xffff0000u);                                       \
    acc = __builtin_elementwise_fma((f32x2){cb, cb}, x, acc);                     \
  }

  for (int e0 = lo; e0 < hi; e0 += 64) {
    int nchunk = min(hi - e0, 64);
    unsigned myse = 0;
    if (e0 + lane < hi) myse = csr_se[e0 + lane];
    int j = 0;
    for (; j + 8 <= nchunk; j += 8) {
      PAIR_BODY(j)
      PAIR_BODY(j + 2)
      PAIR_BODY(j + 4)
      PAIR_BODY(j + 6)
    }
    for (; j < nchunk; j += 2) { PAIR_BODY(j) }
  }
#undef PAIR_BODY

  // sum over basis groups (xor 8, 16) and the two edge halves (xor 32)
  acc.x += __shfl_xor(acc.x, 8, 64);
  acc.y += __shfl_xor(acc.y, 8, 64);
  acc.x += __shfl_xor(acc.x, 16, 64);
  acc.y += __shfl_xor(acc.y, 16, 64);
  acc.x += __shfl_xor(acc.x, 32, 64);
  acc.y += __shfl_xor(acc.y, 32, 64);

  if (lane < 8) {
    float inv = 1.0f / (float)(deg > 0 ? deg : 1);
    unsigned su = *reinterpret_cast<const unsigned*>(Abuf + (size_t)node * KDIM + 64 + c0);
    float sl0 = __uint_as_float(su << 16);
    float sl1 = __uint_as_float(su & 0xffff0000u);
    float2 bv = *reinterpret_cast<const float2*>(bias2 + c0);
    float2 o;
    o.x = acc.x * inv + sl0 + bv.x;
    o.y = acc.y * inv + sl1 + bv.y;
    *reinterpret_cast<float2*>(dout + (size_t)node * OUT_DIM + c0) = o;
  }
}

// ---------------- fused GEMM1 + projection, LDS-aliased to 26KB (5 blocks/CU):
// main loop: As [0,8KB) + Bs [8,24KB); after final barrier Hs [0,16KB) aliases
// As+lower-Bs, B2pt stage Bp [16,26KB). h never touches HBM.
__global__ __launch_bounds__(256) void gemm1p_kernel(const unsigned short* __restrict__ A,
                                                     const unsigned short* __restrict__ B1t,
                                                     const float* __restrict__ bias1,
                                                     const unsigned short* __restrict__ B2pt,
                                                     unsigned short* __restrict__ Abuf, int M) {
  __shared__ unsigned short lds[13312];  // 26 KB
  unsigned short* Asb = lds;             // [0, 4096) shorts: A tile 64x64
  unsigned short* Bsb = lds + 4096;      // [4096, 12288): B tile 128x64
  unsigned short* Hs = lds;              // [0, 8192): h tile 64x128 (after main loop)
  unsigned short* Bp = lds + 8192;       // [8192, 13312): B2pt stage 80x64

  int wave = threadIdx.x >> 6;
  int lane = threadIdx.x & 63;
  int row0 = blockIdx.x * 64;
  int kh = lane >> 4;
  int cl = lane & 15;
  int ar = wave * 16 + cl;
  f32x4 acc[8] = {};

  for (int k0 = 0; k0 < KDIM; k0 += 64) {
#pragma unroll
    for (int p = 0; p < 2; ++p) {
      int cid = threadIdx.x + p * 256;
      int r = cid >> 3, c8 = cid & 7;
      int gr = row0 + r;  // rows >= M read ws garbage; their acc rows are never stored
      gload_lds16(A + (size_t)gr * KDIM + k0 + ((c8 ^ (r & 7)) * 8), Asb + cid * 8);
    }
#pragma unroll
    for (int p = 0; p < 4; ++p) {
      int cid = threadIdx.x + p * 256;
      int r = cid >> 3, c8 = cid & 7;
      gload_lds16(B1t + (size_t)r * KDIM + k0 + ((c8 ^ (r & 7)) * 8), Bsb + cid * 8);
    }
    __syncthreads();
    short8 a0 = *reinterpret_cast<const short8*>(Asb + ar * 64 + ((kh ^ (ar & 7)) * 8));
    short8 a1 = *reinterpret_cast<const short8*>(Asb + ar * 64 + (((4 + kh) ^ (ar & 7)) * 8));
#pragma unroll
    for (int ct = 0; ct < 8; ++ct) {
      int bc = ct * 16 + cl;
      short8 b0 = *reinterpret_cast<const short8*>(Bsb + bc * 64 + ((kh ^ (bc & 7)) * 8));
      short8 b1 = *reinterpret_cast<const short8*>(Bsb + bc * 64 + (((4 + kh) ^ (bc & 7)) * 8));
      acc[ct] = __builtin_amdgcn_mfma_f32_16x16x32_bf16(a0, b0, acc[ct], 0, 0, 0);
      acc[ct] = __builtin_amdgcn_mfma_f32_16x16x32_bf16(a1, b1, acc[ct], 0, 0, 0);
    }
    __syncthreads();
  }

  // epilogue 1: h -> Hs only (16B-chunk XOR swizzle); no global store
  int rb = wave * 16 + (lane >> 4) * 4;  // local row base
#pragma unroll
  for (int ct = 0; ct < 8; ++ct) {
    int col = ct * 16 + cl;
    float bv = bias1[col];
#pragma unroll
    for (int r = 0; r < 4; ++r) {
      int lr = rb + r;
      float v = fmaxf(acc[ct][r] + bv, 0.0f);
      unsigned short hb = f2b(v);
      int c8 = col >> 3;  // 0..15
      int c8s = (c8 & 8) | ((c8 ^ lr) & 7);
      *reinterpret_cast<unsigned short*>(
          reinterpret_cast<char*>(Hs + lr * 128) + c8s * 16 + (col & 7) * 2) = hb;
    }
  }
  __syncthreads();

  // P-GEMM: A = Hs (64x128), B = B2pt [80][128] staged into Bp
  f32x4 acc2[5] = {};
  for (int k0 = 0; k0 < 128; k0 += 64) {
    for (int cid = threadIdx.x; cid < 80 * 8; cid += 256) {
      int r = cid >> 3, c8 = cid & 7;
      short8 v = *reinterpret_cast<const short8*>(B2pt + r * 128 + k0 + c8 * 8);
      *reinterpret_cast<short8*>(Bp + r * 64 + (c8 ^ (r & 7)) * 8) = v;
    }
    __syncthreads();
    int c8a = (k0 >> 3) + kh;
    int c8b = (k0 >> 3) + 4 + kh;
    short8 h0 = *reinterpret_cast<const short8*>(
        reinterpret_cast<char*>(Hs + ar * 128) + (((c8a ^ ar) & 7) | (c8a & 8)) * 16);
    short8 h1 = *reinterpret_cast<const short8*>(
        reinterpret_cast<char*>(Hs + ar * 128) + (((c8b ^ ar) & 7) | (c8b & 8)) * 16);
#pragma unroll
    for (int ct = 0; ct < 5; ++ct) {
      int bc = ct * 16 + cl;
      short8 b0 = *reinterpret_cast<const short8*>(Bp + bc * 64 + ((kh ^ (bc & 7)) * 8));
      short8 b1 = *reinterpret_cast<const short8*>(Bp + bc * 64 + (((4 + kh) ^ (bc & 7)) * 8));
      acc2[ct] = __builtin_amdgcn_mfma_f32_16x16x32_bf16(h0, b0, acc2[ct], 0, 0, 0);
      acc2[ct] = __builtin_amdgcn_mfma_f32_16x16x32_bf16(h1, b1, acc2[ct], 0, 0, 0);
    }
    __syncthreads();
  }

  // epilogue 2: P -> Abuf cols 0:80
#pragma unroll
  for (int ct = 0; ct < 5; ++ct) {
    int col = ct * 16 + cl;
#pragma unroll
    for (int r = 0; r < 4; ++r) {
      int gr = row0 + rb + r;
      if (gr < M) Abuf[(size_t)gr * KDIM + col] = f2b(acc2[ct][r]);
    }
  }
}

extern "C" void kernel_launch(void* const* d_in, const int* in_sizes, int n_in,
                              void* d_out, int out_size, void* d_ws, size_t ws_size,
                              hipStream_t stream) {
  const int* node_ids = (const int*)d_in[0];
  const int* src = (const int*)d_in[1];
  const int* dst = (const int*)d_in[2];
  const int* etype = (const int*)d_in[3];
  const float* emb = (const float*)d_in[4];
  const float* basis1 = (const float*)d_in[5];
  const float* comp1 = (const float*)d_in[6];
  const float* loop_w1 = (const float*)d_in[7];
  const float* bias1 = (const float*)d_in[8];
  const float* basis2 = (const float*)d_in[9];
  const float* comp2 = (const float*)d_in[10];
  const float* loop_w2 = (const float*)d_in[11];
  const float* bias2 = (const float*)d_in[12];
  (void)in_sizes; (void)n_in; (void)out_size; (void)ws_size;

  char* ws = (char*)d_ws;
  size_t off = 0;
  auto alloc = [&](size_t bytes) -> void* {
    void* p = ws + off;
    off += (bytes + 255) & ~(size_t)255;
    return p;
  };
  int* csr_start = (int*)alloc(N_NODES * sizeof(int));
  int* cntA = (int*)alloc(N_NODES * sizeof(int));
  int* cursor = (int*)alloc(N_NODES * sizeof(int));
  int* counter = (int*)alloc(sizeof(int));
  unsigned* csr_se = (unsigned*)alloc((size_t)N_EDGES * sizeof(unsigned));
  unsigned short* Abuf = (unsigned short*)alloc((size_t)N_NODES * KDIM * sizeof(unsigned short));
  unsigned short* B1t = (unsigned short*)alloc(128 * KDIM * sizeof(unsigned short));
  unsigned short* B2pt = (unsigned short*)alloc(80 * 128 * sizeof(unsigned short));

  prologue_kernel<<<CONV_BLOCKS + PREP_BLOCKS + INIT_BLOCKS, 256, 0, stream>>>(
      node_ids, emb, Abuf, basis1, loop_w1, basis2, loop_w2, B1t, B2pt, cntA, counter);
  count_kernel<<<1024, 256, 0, stream>>>(dst, cntA);
  alloc_kernel<<<(N_NODES + 255) / 256, 256, 0, stream>>>(cntA, csr_start, cursor, counter);
  fill_kernel<<<1024, 256, 0, stream>>>(src, dst, etype, cursor, csr_se);

  // layer 1: aggregate x -> y1s (cols 0:512), then fused GEMM:
  // h (LDS only) and P = h*[basis2|loop_w2] -> cols 0:80
  agg_kernel<<<(N_NODES + 3) / 4, 256, 0, stream>>>(csr_start, cntA, csr_se, comp1, Abuf);
  gemm1p_kernel<<<(N_NODES + 63) / 64, 256, 0, stream>>>(Abuf, B1t, bias1, B2pt, Abuf, N_NODES);

  // layer 2: agg over P + self-loop + bias2 -> d_out (fp32)
  agg2_kernel<<<(N_NODES + 3) / 4, 256, 0, stream>>>(csr_start, cntA, csr_se, comp2, Abuf,
                                                     bias2, (float*)d_out);
}

// Round 16
// 142.902 us; speedup vs baseline: 1.0403x; 1.0377x over previous
//
#include <hip/hip_runtime.h>
#include <hip/hip_bf16.h>

#define N_NODES 50000
#define N_EDGES 500000
#define H_DIM 128
#define OUT_DIM 16
#define KDIM 640  // 4*128 (bases) + 128 (self-loop features)

typedef short short8 __attribute__((ext_vector_type(8)));
typedef float f32x4 __attribute__((ext_vector_type(4)));
typedef float f32x2 __attribute__((ext_vector_type(2)));

__device__ inline unsigned short f2b(float f) {
  unsigned u = __float_as_uint(f);
  u += 0x7fffu + ((u >> 16) & 1u);
  return (unsigned short)(u >> 16);
}
__device__ inline float b2f(unsigned short u) {
  return __uint_as_float(((unsigned)u) << 16);
}

// async global->LDS, 16B per lane; LDS dest is wave-uniform base + lane*16 (linear)
__device__ __forceinline__ void gload_lds16(const unsigned short* g, unsigned short* l) {
  __builtin_amdgcn_global_load_lds(
      (const __attribute__((address_space(1))) unsigned int*)g,
      (__attribute__((address_space(3))) unsigned int*)l, 16, 0, 0);
}

// ---------------- fused prologue: convert_x | pack B1t [128][640] + B2pt [80][128] | init
#define CONV_BLOCKS 6250
#define PREP_BLOCKS 360
#define INIT_BLOCKS 196
__global__ void prologue_kernel(const int* __restrict__ node_ids, const float* __restrict__ emb,
                                unsigned short* __restrict__ Abuf,
                                const float* __restrict__ basis1, const float* __restrict__ loop_w1,
                                const float* __restrict__ basis2, const float* __restrict__ loop_w2,
                                unsigned short* __restrict__ B1t, unsigned short* __restrict__ B2pt,
                                int* __restrict__ cntA, int* __restrict__ counter) {
  int b = blockIdx.x;
  if (b < CONV_BLOCKS) {
    int tid = b * 256 + threadIdx.x;  // one per 4 elems
    if (tid >= N_NODES * (H_DIM / 4)) return;
    int n = tid >> 5;
    int q = tid & 31;
    int id = node_ids[n];
    const float4 v = *reinterpret_cast<const float4*>(emb + (size_t)id * H_DIM + q * 4);
    uint2 p;
    p.x = (unsigned)f2b(v.x) | ((unsigned)f2b(v.y) << 16);
    p.y = (unsigned)f2b(v.z) | ((unsigned)f2b(v.w) << 16);
    *reinterpret_cast<uint2*>(Abuf + (size_t)n * KDIM + 512 + q * 4) = p;
  } else if (b < CONV_BLOCKS + PREP_BLOCKS) {
    int tid = (b - CONV_BLOCKS) * 256 + threadIdx.x;
    if (tid < 128 * KDIM) {
      int c = tid / KDIM, k = tid % KDIM;
      float v = (k < 512) ? basis1[k * 128 + c] : loop_w1[(k - 512) * 128 + c];
      B1t[c * KDIM + k] = f2b(v);
    } else if (tid < 128 * KDIM + 80 * 128) {
      int t2 = tid - 128 * KDIM;
      int c = t2 / 128, k = t2 % 128;
      float v = (c < 64) ? basis2[(c >> 4) * 128 * 16 + k * 16 + (c & 15)]
                         : loop_w2[k * 16 + (c - 64)];
      B2pt[c * 128 + k] = f2b(v);
    }
  } else {
    int i = (b - CONV_BLOCKS - PREP_BLOCKS) * 256 + threadIdx.x;
    if (i < N_NODES) cntA[i] = 0;
    if (i == 0) *counter = 0;
  }
}

// ---------------- CSR build (segment allocator; order-free)
__global__ void count_kernel(const int* __restrict__ dst, int* __restrict__ cnt) {
  for (int e = blockIdx.x * blockDim.x + threadIdx.x; e < N_EDGES; e += gridDim.x * blockDim.x)
    atomicAdd(&cnt[dst[e]], 1);
}

__global__ void alloc_kernel(const int* __restrict__ cnt, int* __restrict__ start,
                             int* __restrict__ cursor, int* __restrict__ counter) {
  int i = blockIdx.x * blockDim.x + threadIdx.x;
  int lane = threadIdx.x & 63;
  int c = (i < N_NODES) ? cnt[i] : 0;
  int incl = c;
#pragma unroll
  for (int off = 1; off < 64; off <<= 1) {
    int v = __shfl_up(incl, off, 64);
    if (lane >= off) incl += v;
  }
  int waveTotal = __shfl(incl, 63, 64);
  int base = 0;
  if (lane == 63) base = atomicAdd(counter, waveTotal);
  base = __shfl(base, 63, 64);
  if (i < N_NODES) {
    int v = base + incl - c;
    start[i] = v;
    cursor[i] = v;  // fill's bump-allocator cursor (single atomic per edge)
  }
}

// edge record packed: src in bits 0:15 (N_NODES < 65536), etype in bits 16:31
__global__ void fill_kernel(const int* __restrict__ src, const int* __restrict__ dst,
                            const int* __restrict__ et, int* __restrict__ cursor,
                            unsigned* __restrict__ csr_se) {
  for (int e = blockIdx.x * blockDim.x + threadIdx.x; e < N_EDGES; e += gridDim.x * blockDim.x) {
    int idx = atomicAdd(&cursor[dst[e]], 1);
    csr_se[idx] = (unsigned)src[e] | ((unsigned)et[e] << 16);
  }
}

// ---------------- layer-1 aggregation: y[d,b,i] = (1/deg) * sum_e comp[et,b]*x[src,i]
__global__ __launch_bounds__(256) void agg_kernel(const int* __restrict__ csr_start,
                                                  const int* __restrict__ csr_cnt,
                                                  const unsigned* __restrict__ csr_se,
                                                  const float* __restrict__ comp,
                                                  unsigned short* __restrict__ Abuf) {
  int node = blockIdx.x * 4 + (threadIdx.x >> 6);
  if (node >= N_NODES) return;
  int lane = threadIdx.x & 63;
  int lo = __builtin_amdgcn_readfirstlane(csr_start[node]);
  int deg = __builtin_amdgcn_readfirstlane(csr_cnt[node]);
  int hi = lo + deg;

  f32x2 a0 = {0.f, 0.f}, a1 = {0.f, 0.f}, a2 = {0.f, 0.f}, a3 = {0.f, 0.f};
  const unsigned short* featb = Abuf + 512;
  const int laneoff = lane * 2;  // elements

#define EDGE_BODY(J)                                                                   \
  {                                                                                    \
    unsigned v = __builtin_amdgcn_readlane(myse, (J));                                 \
    int s = (int)(v & 0xFFFFu);                                                        \
    int t = (int)(v >> 16);                                                            \
    unsigned u = *reinterpret_cast<const unsigned*>(featb + s * KDIM + laneoff);       \
    float4 c = *reinterpret_cast<const float4*>(comp + t * 4);                         \
    f32x2 x;                                                                           \
    x.x = __uint_as_float(u << 16);                                                    \
    x.y = __uint_as_float(u & 0xffff0000u);                                            \
    a0 = __builtin_elementwise_fma((f32x2){c.x, c.x}, x, a0);                          \
    a1 = __builtin_elementwise_fma((f32x2){c.y, c.y}, x, a1);                          \
    a2 = __builtin_elementwise_fma((f32x2){c.z, c.z}, x, a2);                          \
    a3 = __builtin_elementwise_fma((f32x2){c.w, c.w}, x, a3);                          \
  }

  for (int e0 = lo; e0 < hi; e0 += 64) {
    int nchunk = min(hi - e0, 64);
    unsigned myse = 0;
    if (e0 + lane < hi) myse = csr_se[e0 + lane];
    int j = 0;
    for (; j + 8 <= nchunk; j += 8) {
      EDGE_BODY(j)
      EDGE_BODY(j + 1)
      EDGE_BODY(j + 2)
      EDGE_BODY(j + 3)
      EDGE_BODY(j + 4)
      EDGE_BODY(j + 5)
      EDGE_BODY(j + 6)
      EDGE_BODY(j + 7)
    }
    if (j + 4 <= nchunk) {
      EDGE_BODY(j)
      EDGE_BODY(j + 1)
      EDGE_BODY(j + 2)
      EDGE_BODY(j + 3)
      j += 4;
    }
    for (; j < nchunk; ++j) { EDGE_BODY(j) }
  }
#undef EDGE_BODY

  float inv = 1.0f / (float)(deg > 0 ? deg : 1);
  unsigned short* out = Abuf + (size_t)node * KDIM;
  unsigned p0w = (unsigned)f2b(a0.x * inv) | ((unsigned)f2b(a0.y * inv) << 16);
  unsigned p1w = (unsigned)f2b(a1.x * inv) | ((unsigned)f2b(a1.y * inv) << 16);
  unsigned p2w = (unsigned)f2b(a2.x * inv) | ((unsigned)f2b(a2.y * inv) << 16);
  unsigned p3w = (unsigned)f2b(a3.x * inv) | ((unsigned)f2b(a3.y * inv) << 16);
  *reinterpret_cast<unsigned*>(out + 0 * 128 + laneoff) = p0w;
  *reinterpret_cast<unsigned*>(out + 1 * 128 + laneoff) = p1w;
  *reinterpret_cast<unsigned*>(out + 2 * 128 + laneoff) = p2w;
  *reinterpret_cast<unsigned*>(out + 3 * 128 + laneoff) = p3w;
}

// ---------------- layer-2 aggregation over projected features (P in Abuf cols 0:80)
// Edge-pair processing: lanes 0-31 take edge j, lanes 32-63 edge j+1; each lane
// loads one dword (2 adjacent P columns) -> no sub-dword loads, half the VMEM ops.
__global__ __launch_bounds__(256) void agg2_kernel(const int* __restrict__ csr_start,
                                                   const int* __restrict__ csr_cnt,
                                                   const unsigned* __restrict__ csr_se,
                                                   const float* __restrict__ comp,
                                                   const unsigned short* __restrict__ Abuf,
                                                   const float* __restrict__ bias2,
                                                   float* __restrict__ dout) {
  int node = blockIdx.x * 4 + (threadIdx.x >> 6);
  if (node >= N_NODES) return;
  int lane = threadIdx.x & 63;
  int eg = lane >> 5;   // which edge of the pair
  int ll = lane & 31;
  int b = ll >> 3;      // basis index (c0>>4 == ll>>3)
  int c0 = ll * 2;      // P column pair (c0, c0+1), < 64
  int lo = __builtin_amdgcn_readfirstlane(csr_start[node]);
  int deg = __builtin_amdgcn_readfirstlane(csr_cnt[node]);
  int hi = lo + deg;

  f32x2 acc = {0.f, 0.f};

#define PAIR_BODY(J)                                                               \
  {                                                                               \
    int idx = (J) + eg;                                                           \
    unsigned v = __shfl(myse, idx, 64);                                           \
    int s = (int)(v & 0xFFFFu);                                                   \
    int t = (int)(v >> 16);                                                       \
    unsigned u = *reinterpret_cast<const unsigned*>(Abuf + (size_t)s * KDIM + c0);\
    float cv = comp[t * 4 + b];                                                   \
    float cb = (idx < nchunk) ? cv : 0.0f;                                        \
    f32x2 x;                                                                      \
    x.x = __uint_as_float(u << 16);                                               \
    x.y = __uint_as_float(u & 0xffff0000u);                                       \
    acc = __builtin_elementwise_fma((f32x2){cb, cb}, x, acc);                     \
  }

  for (int e0 = lo; e0 < hi; e0 += 64) {
    int nchunk = min(hi - e0, 64);
    unsigned myse = 0;
    if (e0 + lane < hi) myse = csr_se[e0 + lane];
    int j = 0;
    for (; j + 8 <= nchunk; j += 8) {
      PAIR_BODY(j)
      PAIR_BODY(j + 2)
      PAIR_BODY(j + 4)
      PAIR_BODY(j + 6)
    }
    for (; j < nchunk; j += 2) { PAIR_BODY(j) }
  }
#undef PAIR_BODY

  // sum over basis groups (xor 8, 16) and the two edge halves (xor 32)
  acc.x += __shfl_xor(acc.x, 8, 64);
  acc.y += __shfl_xor(acc.y, 8, 64);
  acc.x += __shfl_xor(acc.x, 16, 64);
  acc.y += __shfl_xor(acc.y, 16, 64);
  acc.x += __shfl_xor(acc.x, 32, 64);
  acc.y += __shfl_xor(acc.y, 32, 64);

  if (lane < 8) {
    float inv = 1.0f / (float)(deg > 0 ? deg : 1);
    unsigned su = *reinterpret_cast<const unsigned*>(Abuf + (size_t)node * KDIM + 64 + c0);
    float sl0 = __uint_as_float(su << 16);
    float sl1 = __uint_as_float(su & 0xffff0000u);
    float2 bv = *reinterpret_cast<const float2*>(bias2 + c0);
    float2 o;
    o.x = acc.x * inv + sl0 + bv.x;
    o.y = acc.y * inv + sl1 + bv.y;
    *reinterpret_cast<float2*>(dout + (size_t)node * OUT_DIM + c0) = o;
  }
}

// ---------------- fused GEMM1 + projection (R9/R13 version):
// h = relu([y1s|x]*B1t^T + bias1) -> Hs (LDS only; h is dead globally)
// P = h * B2pt^T                  -> Abuf cols 0:80  (K=128, NC=80)
__global__ __launch_bounds__(256) void gemm1p_kernel(const unsigned short* __restrict__ A,
                                                     const unsigned short* __restrict__ B1t,
                                                     const float* __restrict__ bias1,
                                                     const unsigned short* __restrict__ B2pt,
                                                     unsigned short* __restrict__ Abuf, int M) {
  __shared__ unsigned short As[64][64];
  __shared__ unsigned short Bs[128][64];
  __shared__ unsigned short Hs[64][128];  // h tile, 16B-chunk XOR swizzled
  int wave = threadIdx.x >> 6;
  int lane = threadIdx.x & 63;
  int row0 = blockIdx.x * 64;
  int kh = lane >> 4;
  int cl = lane & 15;
  int ar = wave * 16 + cl;
  f32x4 acc[8] = {};

  for (int k0 = 0; k0 < KDIM; k0 += 64) {
#pragma unroll
    for (int p = 0; p < 2; ++p) {
      int cid = threadIdx.x + p * 256;
      int r = cid >> 3, c8 = cid & 7;
      int gr = row0 + r;  // rows >= M read ws garbage; their acc rows are never stored
      gload_lds16(A + (size_t)gr * KDIM + k0 + ((c8 ^ (r & 7)) * 8), &As[0][0] + cid * 8);
    }
#pragma unroll
    for (int p = 0; p < 4; ++p) {
      int cid = threadIdx.x + p * 256;
      int r = cid >> 3, c8 = cid & 7;
      gload_lds16(B1t + (size_t)r * KDIM + k0 + ((c8 ^ (r & 7)) * 8), &Bs[0][0] + cid * 8);
    }
    __syncthreads();
    short8 a0 = *reinterpret_cast<const short8*>(&As[ar][((kh) ^ (ar & 7)) * 8]);
    short8 a1 = *reinterpret_cast<const short8*>(&As[ar][((4 + kh) ^ (ar & 7)) * 8]);
#pragma unroll
    for (int ct = 0; ct < 8; ++ct) {
      int bc = ct * 16 + cl;
      short8 b0 = *reinterpret_cast<const short8*>(&Bs[bc][((kh) ^ (bc & 7)) * 8]);
      short8 b1 = *reinterpret_cast<const short8*>(&Bs[bc][((4 + kh) ^ (bc & 7)) * 8]);
      acc[ct] = __builtin_amdgcn_mfma_f32_16x16x32_bf16(a0, b0, acc[ct], 0, 0, 0);
      acc[ct] = __builtin_amdgcn_mfma_f32_16x16x32_bf16(a1, b1, acc[ct], 0, 0, 0);
    }
    __syncthreads();
  }

  // epilogue 1: h -> Hs only (swizzled); no global store (h unused downstream)
  int rb = wave * 16 + (lane >> 4) * 4;  // local row base
#pragma unroll
  for (int ct = 0; ct < 8; ++ct) {
    int col = ct * 16 + cl;
    float bv = bias1[col];
#pragma unroll
    for (int r = 0; r < 4; ++r) {
      int lr = rb + r;
      float v = fmaxf(acc[ct][r] + bv, 0.0f);
      unsigned short hb = f2b(v);
      int c8 = col >> 3;  // 0..15
      int c8s = (c8 & 8) | ((c8 ^ lr) & 7);
      *reinterpret_cast<unsigned short*>(
          reinterpret_cast<char*>(&Hs[lr][0]) + c8s * 16 + (col & 7) * 2) = hb;
    }
  }
  __syncthreads();

  // P-GEMM: A = Hs (64x128), B = B2pt [80][128] staged into Bs
  f32x4 acc2[5] = {};
  for (int k0 = 0; k0 < 128; k0 += 64) {
    for (int cid = threadIdx.x; cid < 80 * 8; cid += 256) {
      int r = cid >> 3, c8 = cid & 7;
      short8 v = *reinterpret_cast<const short8*>(B2pt + r * 128 + k0 + c8 * 8);
      *reinterpret_cast<short8*>(&Bs[r][(c8 ^ (r & 7)) * 8]) = v;
    }
    __syncthreads();
    int c8a = (k0 >> 3) + kh;
    int c8b = (k0 >> 3) + 4 + kh;
    short8 a0 = *reinterpret_cast<const short8*>(
        reinterpret_cast<char*>(&Hs[ar][0]) + (((c8a ^ ar) & 7) | (c8a & 8)) * 16);
    short8 a1 = *reinterpret_cast<const short8*>(
        reinterpret_cast<char*>(&Hs[ar][0]) + (((c8b ^ ar) & 7) | (c8b & 8)) * 16);
#pragma unroll
    for (int ct = 0; ct < 5; ++ct) {
      int bc = ct * 16 + cl;
      short8 b0 = *reinterpret_cast<const short8*>(&Bs[bc][((kh) ^ (bc & 7)) * 8]);
      short8 b1 = *reinterpret_cast<const short8*>(&Bs[bc][((4 + kh) ^ (bc & 7)) * 8]);
      acc2[ct] = __builtin_amdgcn_mfma_f32_16x16x32_bf16(a0, b0, acc2[ct], 0, 0, 0);
      acc2[ct] = __builtin_amdgcn_mfma_f32_16x16x32_bf16(a1, b1, acc2[ct], 0, 0, 0);
    }
    __syncthreads();
  }

  // epilogue 2: P -> Abuf cols 0:80
#pragma unroll
  for (int ct = 0; ct < 5; ++ct) {
    int col = ct * 16 + cl;
#pragma unroll
    for (int r = 0; r < 4; ++r) {
      int gr = row0 + rb + r;
      if (gr < M) Abuf[(size_t)gr * KDIM + col] = f2b(acc2[ct][r]);
    }
  }
}

extern "C" void kernel_launch(void* const* d_in, const int* in_sizes, int n_in,
                              void* d_out, int out_size, void* d_ws, size_t ws_size,
                              hipStream_t stream) {
  const int* node_ids = (const int*)d_in[0];
  const int* src = (const int*)d_in[1];
  const int* dst = (const int*)d_in[2];
  const int* etype = (const int*)d_in[3];
  const float* emb = (const float*)d_in[4];
  const float* basis1 = (const float*)d_in[5];
  const float* comp1 = (const float*)d_in[6];
  const float* loop_w1 = (const float*)d_in[7];
  const float* bias1 = (const float*)d_in[8];
  const float* basis2 = (const float*)d_in[9];
  const float* comp2 = (const float*)d_in[10];
  const float* loop_w2 = (const float*)d_in[11];
  const float* bias2 = (const float*)d_in[12];
  (void)in_sizes; (void)n_in; (void)out_size; (void)ws_size;

  char* ws = (char*)d_ws;
  size_t off = 0;
  auto alloc = [&](size_t bytes) -> void* {
    void* p = ws + off;
    off += (bytes + 255) & ~(size_t)255;
    return p;
  };
  int* csr_start = (int*)alloc(N_NODES * sizeof(int));
  int* cntA = (int*)alloc(N_NODES * sizeof(int));
  int* cursor = (int*)alloc(N_NODES * sizeof(int));
  int* counter = (int*)alloc(sizeof(int));
  unsigned* csr_se = (unsigned*)alloc((size_t)N_EDGES * sizeof(unsigned));
  unsigned short* Abuf = (unsigned short*)alloc((size_t)N_NODES * KDIM * sizeof(unsigned short));
  unsigned short* B1t = (unsigned short*)alloc(128 * KDIM * sizeof(unsigned short));
  unsigned short* B2pt = (unsigned short*)alloc(80 * 128 * sizeof(unsigned short));

  prologue_kernel<<<CONV_BLOCKS + PREP_BLOCKS + INIT_BLOCKS, 256, 0, stream>>>(
      node_ids, emb, Abuf, basis1, loop_w1, basis2, loop_w2, B1t, B2pt, cntA, counter);
  count_kernel<<<1024, 256, 0, stream>>>(dst, cntA);
  alloc_kernel<<<(N_NODES + 255) / 256, 256, 0, stream>>>(cntA, csr_start, cursor, counter);
  fill_kernel<<<1024, 256, 0, stream>>>(src, dst, etype, cursor, csr_se);

  // layer 1: aggregate x -> y1s (cols 0:512), then fused GEMM:
  // h (LDS only) and P = h*[basis2|loop_w2] -> cols 0:80
  agg_kernel<<<(N_NODES + 3) / 4, 256, 0, stream>>>(csr_start, cntA, csr_se, comp1, Abuf);
  gemm1p_kernel<<<(N_NODES + 63) / 64, 256, 0, stream>>>(Abuf, B1t, bias1, B2pt, Abuf, N_NODES);

  // layer 2: agg over P + self-loop + bias2 -> d_out (fp32)
  agg2_kernel<<<(N_NODES + 3) / 4, 256, 0, stream>>>(csr_start, cntA, csr_se, comp2, Abuf,
                                                     bias2, (float*)d_out);
}